// Round 7
// baseline (1047.116 us; speedup 1.0000x reference)
//
#include <hip/hip_runtime.h>
#include <hip/hip_cooperative_groups.h>

namespace cg = cooperative_groups;

typedef __attribute__((ext_vector_type(8))) short short8;
typedef __attribute__((ext_vector_type(4))) float f32x4;
typedef __attribute__((ext_vector_type(2))) float f32x2;

#define NBMAX 512
#define CAP 8192   // per-bucket stage capacity; mean load 4096, sigma ~64

__device__ inline unsigned short f2bf(float f) {
  union { float f; unsigned u; } v; v.f = f;
  unsigned r = v.u + 0x7fffu + ((v.u >> 16) & 1u);
  return (unsigned short)(r >> 16);
}

// packed accumulate: uint4 of 8 bf16 -> 4x f32x2 (v_pk_add_f32)
__device__ inline void addf2(f32x2 (&a)[4], uint4 v) {
  union { uint2 u; f32x2 f; } t;
  t.u.x = v.x << 16; t.u.y = v.x & 0xffff0000u; a[0] += t.f;
  t.u.x = v.y << 16; t.u.y = v.y & 0xffff0000u; a[1] += t.f;
  t.u.x = v.z << 16; t.u.y = v.z & 0xffff0000u; a[2] += t.f;
  t.u.x = v.w << 16; t.u.y = v.w & 0xffff0000u; a[3] += t.f;
}

__device__ inline int load_src(const int* ei, int E, int e, int f64) {
  return f64 ? ei[2 * e] : ei[e];
}
__device__ inline int load_dst(const int* ei, int E, int e, int f64) {
  return f64 ? ei[2 * (E + e)] : ei[E + e];
}

// ---------------- agg phase: M[n] = inv[n] * sum_{j in N(n)} A[j] ----------------
// Round-3 agg_mean body, grid-strided, 8 waves/block. One wave per 2 nodes;
// 4 edge-slots x 16 column-lanes; batch-prefetch. No LDS, no block barriers.
__device__ void agg_phase(const unsigned short* __restrict__ A,
                          const float* __restrict__ inv,
                          const int* __restrict__ offs,
                          const int* __restrict__ cnt,
                          const int* __restrict__ csr,
                          unsigned short* __restrict__ M, int n) {
  const int t = threadIdx.x;
  const int lane = t & 63;
  const int wave = t >> 6;
  const int g = lane >> 4;      // edge slot 0..3
  const int l = lane & 15;      // column chunk: columns l*8 .. l*8+7
  const char* Ab = (const char*)A + (size_t)l * 16;
  const int units = (((n + 1) >> 1) + 7) >> 3;   // 8 pairs per block

  for (int u = blockIdx.x; u < units; u += gridDim.x) {
    const int pr = u * 8 + wave;
    const int n0 = pr * 2;
    if (n0 >= n) continue;
    const int n1 = n0 + 1;
    const bool has1 = (n1 < n);
    const int deg0 = cnt[n0];
    const int deg1 = has1 ? cnt[n1] : 0;
    const int start = offs[n0];
    const int T = deg0 + deg1;    // CSR rows adjacent -> combined segment
    f32x2 acc0[4] = {{0.f, 0.f}, {0.f, 0.f}, {0.f, 0.f}, {0.f, 0.f}};
    f32x2 acc1[4] = {{0.f, 0.f}, {0.f, 0.f}, {0.f, 0.f}, {0.f, 0.f}};

    if (T <= 64) {
      int offb = ((lane < T) ? csr[start + lane] : 0) << 8;
      {
        int nb2[8];
        uint4 vv[8];
#pragma unroll
        for (int j = 0; j < 8; ++j) nb2[j] = __shfl(offb, j * 4 + g);
#pragma unroll
        for (int j = 0; j < 8; ++j)
          vv[j] = *(const uint4*)(Ab + (size_t)(unsigned)nb2[j]);
#pragma unroll
        for (int j = 0; j < 8; ++j) {
          int e = j * 4 + g;
          if (e < deg0) addf2(acc0, vv[j]);
          else if (e < T) addf2(acc1, vv[j]);
        }
      }
      if (T > 32) {
        int nb2[8];
        uint4 vv[8];
#pragma unroll
        for (int j = 0; j < 8; ++j) nb2[j] = __shfl(offb, 32 + j * 4 + g);
#pragma unroll
        for (int j = 0; j < 8; ++j)
          vv[j] = *(const uint4*)(Ab + (size_t)(unsigned)nb2[j]);
#pragma unroll
        for (int j = 0; j < 8; ++j) {
          int e = 32 + j * 4 + g;
          if (e < deg0) addf2(acc0, vv[j]);
          else if (e < T) addf2(acc1, vv[j]);
        }
      }
    } else {
      // rare generic path (T > 64 essentially never at mean degree 16)
      for (int node = 0; node < 2; ++node) {
        int dg = node ? deg1 : deg0;
        int st = node ? (start + deg0) : start;
        for (int base = 0; base < dg; base += 64) {
          int m = dg - base;
          if (m > 64) m = 64;
          int offb = ((lane < m) ? csr[st + base + lane] : 0) << 8;
#pragma unroll 4
          for (int i = 0; i < m; i += 4) {
            int sl = i + g;
            int nbv = __shfl(offb, sl & 63);  // full-exec shfl
            if (sl < m) {
              uint4 v = *(const uint4*)(Ab + (size_t)(unsigned)nbv);
              if (node) addf2(acc1, v);
              else addf2(acc0, v);
            }
          }
        }
      }
    }

    // reduce the 4 edge-slots (lanes differing in bits 4..5)
#pragma unroll
    for (int k = 0; k < 4; ++k) {
      acc0[k].x += __shfl_xor(acc0[k].x, 16);
      acc0[k].x += __shfl_xor(acc0[k].x, 32);
      acc0[k].y += __shfl_xor(acc0[k].y, 16);
      acc0[k].y += __shfl_xor(acc0[k].y, 32);
      acc1[k].x += __shfl_xor(acc1[k].x, 16);
      acc1[k].x += __shfl_xor(acc1[k].x, 32);
      acc1[k].y += __shfl_xor(acc1[k].y, 16);
      acc1[k].y += __shfl_xor(acc1[k].y, 32);
    }

    const int c0 = l * 8 + g * 2;
    {
      float s = inv[n0];
      unsigned pkt = (unsigned)f2bf(acc0[g].x * s) |
                     ((unsigned)f2bf(acc0[g].y * s) << 16);
      *(unsigned*)(M + (size_t)n0 * 128 + c0) = pkt;
    }
    if (has1) {
      float s = inv[n1];
      unsigned pkt = (unsigned)f2bf(acc1[g].x * s) |
                     ((unsigned)f2bf(acc1[g].y * s) << 16);
      *(unsigned*)(M + (size_t)n1 * 128 + c0) = pkt;
    }
  }
}

// ---------------- gemm phase: out = Am@Wl^T + As@Wr^T + b (+relu) ----------------
// Round-3 gemm_fused body, 8 waves/block (128-row chunks). Wl+Wr staged once
// into the FULL 64 KiB shared buffer (fixes round-6 OOB), then barrier-free.
template <int RELU, int OUTBF>
__device__ void gemm_phase(const unsigned short* __restrict__ Am,
                           const unsigned short* __restrict__ As,
                           const unsigned short* __restrict__ Wp,
                           const float* __restrict__ bias,
                           void* __restrict__ outp, int n,
                           unsigned short* wsh) {
  const int tid = threadIdx.x;
  {
    const uint4* wsrc = (const uint4*)Wp;
    uint4* wdst = (uint4*)wsh;
#pragma unroll
    for (int it = 0; it < 8; ++it)   // 8 * 512 * 16B = 64 KiB
      wdst[it * 512 + tid] = wsrc[it * 512 + tid];
  }
  __syncthreads();

  const int lane = tid & 63;
  const int wave = tid >> 6;
  const int nn = lane & 15;
  const int quad = lane >> 4;
  const int nch = (n + 127) >> 7;   // 128-row chunks (8 waves x 16 rows)

  for (int ch = blockIdx.x; ch < nch; ch += gridDim.x) {
    const int rowbase = ch * 128 + wave * 16;
    int nodeA = rowbase + nn;
    if (nodeA > n - 1) nodeA = n - 1;

    short8 am[4], asf[4];
#pragma unroll
    for (int s = 0; s < 4; ++s) {
      am[s] = *(const short8*)(Am + (size_t)nodeA * 128 + s * 32 + quad * 8);
      asf[s] = *(const short8*)(As + (size_t)nodeA * 128 + s * 32 + quad * 8);
    }

    f32x4 acc[8];
#pragma unroll
    for (int jt = 0; jt < 8; ++jt) acc[jt] = (f32x4){0.f, 0.f, 0.f, 0.f};

#pragma unroll
    for (int jt = 0; jt < 8; ++jt) {
#pragma unroll
      for (int s = 0; s < 4; ++s) {
        int c = (s * 8 + jt) * 4 + quad;
        short8 bl = *(const short8*)(wsh + (c * 16 + nn) * 8);
        short8 br = *(const short8*)(wsh + 16384 + (c * 16 + nn) * 8);
        acc[jt] = __builtin_amdgcn_mfma_f32_16x16x32_bf16(am[s], bl, acc[jt], 0, 0, 0);
        acc[jt] = __builtin_amdgcn_mfma_f32_16x16x32_bf16(asf[s], br, acc[jt], 0, 0, 0);
      }
    }

#pragma unroll
    for (int jt = 0; jt < 8; ++jt) {
      int col = jt * 16 + nn;
      float bv = bias[col];
#pragma unroll
      for (int r = 0; r < 4; ++r) {
        int ro = rowbase + quad * 4 + r;
        if (ro < n) {
          float o = acc[jt][r] + bv;
          if (RELU) o = fmaxf(o, 0.f);
          if (OUTBF) {
            ((unsigned short*)outp)[(size_t)ro * 128 + col] = f2bf(o);
          } else {
            ((float*)outp)[(size_t)ro * 128 + col] = o;
          }
        }
      }
    }
  }
}

// ---------------- cooperative mega-kernel: all 6 phases, 1 dispatch ----------------
// 512-thread blocks: 2 blocks/CU with 64 KiB LDS -> 16 waves/CU for the agg
// phases AND a full Wl+Wr LDS image for the gemm phases.
// P0: edge scatter + x->bf16 cast + W permute
// P1: CSR bucket fill
// P2: L1 agg   P3: L1 gemm   P4: L2 agg   P5: L2 gemm
__global__ __launch_bounds__(512, 4) void mega(
    const int* __restrict__ ei, int E, int SB, int N, int nb, int n8,
    const float* __restrict__ x,
    const float* __restrict__ W1l, const float* __restrict__ b1,
    const float* __restrict__ W1r, const float* __restrict__ W2l,
    const float* __restrict__ b2, const float* __restrict__ W2r,
    int* btot, int2* stage, int* cnt, int* offs, float* inv, int* csr,
    unsigned short* Mb, unsigned short* Wp, unsigned short* xb,
    unsigned short* hb, float* out) {
  __shared__ __align__(16) int sbuf[16384];   // 64 KiB
  cg::grid_group gg = cg::this_grid();
  const int t = threadIdx.x;

  // ---- P0a: edge scatter into bucket stage (4096-edge chunks, 8/thread) ----
  {
    int* lcnt = sbuf;              // [NBMAX]
    int* lbase = sbuf + NBMAX;     // [NBMAX]
    int* sflag = sbuf + 2 * NBMAX;
    for (int c = blockIdx.x; c < SB; c += gridDim.x) {
      if (t == 0) *sflag = 0;
      for (int i = t; i < NBMAX; i += 512) lcnt[i] = 0;
      __syncthreads();
      const int e0 = c * 4096;
      {
        int e = e0 + t;
        int v = (e < E) ? ei[2 * e + 1] : 0;   // in-bounds under both layouts
        if (v) atomicOr(sflag, 1);
      }
      __syncthreads();
      const int f64 = (*sflag == 0) ? 1 : 0;

      int srcs[8], bks[8], dsts[8];
#pragma unroll
      for (int i = 0; i < 8; ++i) {
        int e = e0 + i * 512 + t;
        if (e < E) {
          srcs[i] = load_src(ei, E, e, f64);
          int d = load_dst(ei, E, e, f64);
          dsts[i] = d;
          bks[i] = d >> 8;
          atomicAdd(&lcnt[d >> 8], 1);
        } else {
          bks[i] = -1;
        }
      }
      __syncthreads();
      for (int i = t; i < NBMAX; i += 512) {
        int cc = lcnt[i];
        lbase[i] = cc ? atomicAdd(&btot[i], cc) : 0;
      }
      __syncthreads();
      for (int i = t; i < NBMAX; i += 512) lcnt[i] = 0;
      __syncthreads();
#pragma unroll
      for (int i = 0; i < 8; ++i) {
        int bk = bks[i];
        if (bk >= 0) {
          int r = atomicAdd(&lcnt[bk], 1);
          stage[(size_t)bk * CAP + lbase[bk] + r] = make_int2(srcs[i], dsts[i]);
        }
      }
      __syncthreads();   // protect lcnt/lbase before next chunk
    }
  }

  // ---- P0b: x -> bf16 cast (all blocks) ----
  for (int i = blockIdx.x * 512 + t; i < n8; i += gridDim.x * 512) {
    float4 v0 = ((const float4*)x)[2 * i];
    float4 v1 = ((const float4*)x)[2 * i + 1];
    union { unsigned short u[8]; uint4 v; } tv;
    tv.u[0] = f2bf(v0.x); tv.u[1] = f2bf(v0.y);
    tv.u[2] = f2bf(v0.z); tv.u[3] = f2bf(v0.w);
    tv.u[4] = f2bf(v1.x); tv.u[5] = f2bf(v1.y);
    tv.u[6] = f2bf(v1.z); tv.u[7] = f2bf(v1.w);
    ((uint4*)xb)[i] = tv.v;
  }

  // ---- P0c: W cast + permute into MFMA fragment order (blocks 0..3) ----
  if (blockIdx.x < 4) {
    const int m = blockIdx.x;
    const float* W = (m == 0) ? W1l : (m == 1) ? W1r : (m == 2) ? W2l : W2r;
    unsigned short* dst = Wp + (size_t)m * 16384;
#pragma unroll
    for (int it = 0; it < 4; ++it) {   // 4 * 512 = 2048 = 128*16 ids
      int id = it * 512 + t;
      int j = id >> 4;
      int kc = id & 15;
      int s = kc >> 2, q = kc & 3;
      int jt = j >> 4, nn2 = j & 15;
      int c = (s * 8 + jt) * 4 + q;
      const float* src = W + j * 128 + kc * 8;
      union { unsigned short u[8]; uint4 v; } tv;
#pragma unroll
      for (int k = 0; k < 8; ++k) tv.u[k] = f2bf(src[k]);
      *(uint4*)(dst + (c * 16 + nn2) * 8) = tv.v;
    }
  }

  __threadfence();
  gg.sync();

  // ---- P1: CSR bucket fill ----
  {
    int* lhist = sbuf;         // [256]
    int* lscan = sbuf + 256;   // [256]
    int* lcur = sbuf + 512;    // [256]
    int* red = sbuf + 768;     // [512]
    for (int b = blockIdx.x; b < nb; b += gridDim.x) {
      int sum = 0;
      for (int j = t; j < b; j += 512) sum += btot[j];
      red[t] = sum;
      if (t < 256) lhist[t] = 0;
      __syncthreads();
      for (int d = 256; d; d >>= 1) {
        if (t < d) red[t] += red[t + d];
        __syncthreads();
      }
      const int base = red[0];
      const int count = btot[b];
      const int2* sp = stage + (size_t)b * CAP;
      for (int i = t; i < count; i += 512)
        atomicAdd(&lhist[sp[i].y & 255], 1);
      __syncthreads();
      int v = (t < 256) ? lhist[t] : 0;
      if (t < 256) lscan[t] = v;
      __syncthreads();
      for (int d = 1; d < 256; d <<= 1) {
        int tv = (t >= d && t < 256) ? lscan[t - d] : 0;
        __syncthreads();
        if (t < 256) lscan[t] += tv;
        __syncthreads();
      }
      if (t < 256) {
        const int excl = lscan[t] - v;
        const int node = b * 256 + t;
        if (node < N) {
          offs[node] = base + excl;
          cnt[node] = v;
          inv[node] = 1.0f / (float)((v > 1) ? v : 1);
        }
        lcur[t] = base + excl;
      }
      __syncthreads();
      for (int i = t; i < count; i += 512) {
        int2 sd = sp[i];
        int p2 = atomicAdd(&lcur[sd.y & 255], 1);
        csr[p2] = sd.x;
      }
      __syncthreads();   // protect LDS before next bucket
    }
  }

  __threadfence();
  gg.sync();

  // ---- P2: layer-1 aggregate: M1 = mean_agg(xb) ----
  agg_phase(xb, inv, offs, cnt, csr, Mb, N);
  __threadfence();
  gg.sync();

  // ---- P3: layer-1 gemm: hb = relu(M1@W1l^T + xb@W1r^T + b1), bf16 ----
  gemm_phase<1, 1>(Mb, xb, Wp, b1, (void*)hb, N, (unsigned short*)sbuf);
  __threadfence();
  gg.sync();

  // ---- P4: layer-2 aggregate: M2 = mean_agg(hb) ----
  agg_phase(hb, inv, offs, cnt, csr, Mb, N);
  __threadfence();
  gg.sync();

  // ---- P5: layer-2 gemm: out = M2@W2l^T + hb@W2r^T + b2, f32 ----
  gemm_phase<0, 0>(Mb, hb, Wp + 32768, b2, (void*)out, N, (unsigned short*)sbuf);
}

// ---------------- launch ----------------
// One cooperative dispatch for the whole pipeline (+ the btot memset).
// Buffers: xb (bf16 x) lives in d_out (dead before P5 writes it);
//          stage/hb share a ws region (stage dead after P1).

extern "C" void kernel_launch(void* const* d_in, const int* in_sizes, int n_in,
                              void* d_out, int out_size, void* d_ws, size_t ws_size,
                              hipStream_t stream) {
  const float* x = (const float*)d_in[0];
  const int* ei = (const int*)d_in[1];
  const float* W1l = (const float*)d_in[2];
  const float* b1 = (const float*)d_in[3];
  const float* W1r = (const float*)d_in[4];
  const float* W2l = (const float*)d_in[5];
  const float* b2 = (const float*)d_in[6];
  const float* W2r = (const float*)d_in[7];
  float* out = (float*)d_out;

  const int N = in_sizes[0] / 128;
  const int E = in_sizes[1] / 2;
  const int nb = (N + 255) / 256;   // buckets of 256 nodes; must be <= NBMAX

  char* p = (char*)d_ws;
  auto alloc = [&](size_t bytes) {
    char* r = p;
    p += (bytes + 255) & ~(size_t)255;
    return r;
  };
  int* btot = (int*)alloc((size_t)NBMAX * 4);
  int* cnt = (int*)alloc((size_t)N * 4);
  int* offs = (int*)alloc((size_t)N * 4);
  float* inv = (float*)alloc((size_t)N * 4);
  int* csr = (int*)alloc((size_t)E * 4);
  unsigned short* Mb = (unsigned short*)alloc((size_t)N * 128 * 2);    // 25.6 MB
  unsigned short* Wpb = (unsigned short*)alloc((size_t)4 * 16384 * 2); // 128 KB
  size_t stage_bytes = (size_t)nb * CAP * 8;
  size_t hb_bytes = (size_t)N * 128 * 2;
  char* shared_region = alloc(stage_bytes > hb_bytes ? stage_bytes : hb_bytes);
  unsigned short* hb = (unsigned short*)shared_region;  // h (bf16) after CSR done
  int2* stage = (int2*)shared_region;                   // staging during CSR build
  unsigned short* xb = (unsigned short*)d_out;          // bf16 x parked in d_out

  const int SB = (E + 4095) / 4096;
  const int n8 = N * 128 / 8;

  // cooperative grid: exactly co-resident capacity (cached once)
  static int coop_grid = 0;
  if (coop_grid == 0) {
    int dev = 0;
    hipGetDevice(&dev);
    hipDeviceProp_t props;
    hipGetDeviceProperties(&props, dev);
    int bpm = 0;
    if (hipOccupancyMaxActiveBlocksPerMultiprocessor(&bpm, mega, 512, 0) != hipSuccess || bpm <= 0)
      bpm = 1;   // conservative fallback (64 KiB LDS -> at least 1)
    long g = (long)bpm * props.multiProcessorCount;
    if (g < 64) g = 64;
    if (g > 2048) g = 2048;
    coop_grid = (int)g;
  }

  hipMemsetAsync(btot, 0, (size_t)nb * 4, stream);

  int E_ = E, SB_ = SB, N_ = N, nb_ = nb, n8_ = n8;
  void* args[] = {
      (void*)&ei, (void*)&E_, (void*)&SB_, (void*)&N_, (void*)&nb_, (void*)&n8_,
      (void*)&x, (void*)&W1l, (void*)&b1, (void*)&W1r, (void*)&W2l,
      (void*)&b2, (void*)&W2r, (void*)&btot, (void*)&stage, (void*)&cnt,
      (void*)&offs, (void*)&inv, (void*)&csr, (void*)&Mb, (void*)&Wpb,
      (void*)&xb, (void*)&hb, (void*)&out};
  hipLaunchCooperativeKernel((const void*)mega, dim3(coop_grid), dim3(512),
                             args, 0, stream);
}

// Round 8
// 343.135 us; speedup vs baseline: 3.0516x; 3.0516x over previous
//
#include <hip/hip_runtime.h>

typedef __attribute__((ext_vector_type(8))) short short8;
typedef __attribute__((ext_vector_type(4))) float f32x4;
typedef __attribute__((ext_vector_type(2))) float f32x2;

#define NBMAX 512
#define CAP 8192   // per-bucket stage capacity; mean load 4096, sigma ~64

__device__ inline unsigned short f2bf(float f) {
  union { float f; unsigned u; } v; v.f = f;
  unsigned r = v.u + 0x7fffu + ((v.u >> 16) & 1u);
  return (unsigned short)(r >> 16);
}

// packed accumulate: uint4 of 8 bf16 -> 4x f32x2 (v_pk_add_f32)
__device__ inline void addf2(f32x2 (&a)[4], uint4 v) {
  union { uint2 u; f32x2 f; } t;
  t.u.x = v.x << 16; t.u.y = v.x & 0xffff0000u; a[0] += t.f;
  t.u.x = v.y << 16; t.u.y = v.y & 0xffff0000u; a[1] += t.f;
  t.u.x = v.z << 16; t.u.y = v.z & 0xffff0000u; a[2] += t.f;
  t.u.x = v.w << 16; t.u.y = v.w & 0xffff0000u; a[3] += t.f;
}

__device__ inline int load_src(const int* ei, int E, int e, int f64) {
  return f64 ? ei[2 * e] : ei[e];
}
__device__ inline int load_dst(const int* ei, int E, int e, int f64) {
  return f64 ? ei[2 * (E + e)] : ei[E + e];
}

// ---------------- prep: scatter (CSR phase A) + x->bf16 cast + W permute ----------------
// One launch, three block ranges:
//   [0, SB)        : edge scatter into bucket stage (dst>>8 buckets), 2048/block
//   [SB, SB+4)     : one-time W cast+permute into MFMA B-fragment order
//   [SB+4, ...)    : x (f32) -> xb (bf16) streaming cast
// Staged edge is PACKED to 4B: (src << 8) | (dst & 255)  [src < 2^24].
__global__ __launch_bounds__(256) void prep(
    const int* __restrict__ ei, int E,
    int* __restrict__ btot, unsigned* __restrict__ stage, int SB,
    const float* __restrict__ x, unsigned short* __restrict__ xb, int n8,
    const float* __restrict__ W1l, const float* __restrict__ W1r,
    const float* __restrict__ W2l, const float* __restrict__ W2r,
    unsigned short* __restrict__ Wp) {
  __shared__ int lcnt[NBMAX];
  __shared__ int lbase[NBMAX];
  __shared__ int sflag;
  const int b = blockIdx.x;
  const int t = threadIdx.x;

  if (b < SB) {
    // ---- scatter (2048 edges per block) ----
    if (t == 0) sflag = 0;
    for (int i = t; i < NBMAX; i += 256) lcnt[i] = 0;
    __syncthreads();
    const int e0 = b * 2048;
    {
      int e = e0 + t;
      int v = (e < E) ? ei[2 * e + 1] : 0;   // in-bounds under both layouts
      if (v) atomicOr(&sflag, 1);
    }
    __syncthreads();
    const int f64 = (sflag == 0) ? 1 : 0;

    unsigned pk[8];
    int bks[8];
#pragma unroll
    for (int i = 0; i < 8; ++i) {
      int e = e0 + i * 256 + t;
      if (e < E) {
        int s = load_src(ei, E, e, f64);
        int d = load_dst(ei, E, e, f64);
        pk[i] = ((unsigned)s << 8) | ((unsigned)d & 255u);
        bks[i] = d >> 8;
        atomicAdd(&lcnt[d >> 8], 1);
      } else {
        bks[i] = -1;
      }
    }
    __syncthreads();
    for (int i = t; i < NBMAX; i += 256) {
      int c = lcnt[i];
      lbase[i] = c ? atomicAdd(&btot[i], c) : 0;
    }
    __syncthreads();
    for (int i = t; i < NBMAX; i += 256) lcnt[i] = 0;
    __syncthreads();
#pragma unroll
    for (int i = 0; i < 8; ++i) {
      int bk = bks[i];
      if (bk >= 0) {
        int r = atomicAdd(&lcnt[bk], 1);
        stage[(size_t)bk * CAP + lbase[bk] + r] = pk[i];
      }
    }
    return;
  }

  if (b < SB + 4) {
    // ---- W cast + permute (grid-invariant, done once) ----
    const int m = b - SB;
    const float* W = (m == 0) ? W1l : (m == 1) ? W1r : (m == 2) ? W2l : W2r;
    unsigned short* dst = Wp + (size_t)m * 16384;
#pragma unroll
    for (int it = 0; it < 8; ++it) {
      int id = it * 256 + t;
      int j = id >> 4;
      int kc = id & 15;
      int s = kc >> 2, q = kc & 3;
      int jt = j >> 4, nn2 = j & 15;
      int c = (s * 8 + jt) * 4 + q;
      const float* src = W + j * 128 + kc * 8;
      union { unsigned short u[8]; uint4 v; } tv;
#pragma unroll
      for (int k = 0; k < 8; ++k) tv.u[k] = f2bf(src[k]);
      *(uint4*)(dst + (c * 16 + nn2) * 8) = tv.v;
    }
    return;
  }

  // ---- x -> bf16 cast ----
  const int cb = b - SB - 4;
  const int nxb = gridDim.x - SB - 4;
  int i = cb * 256 + t;
  const int stride = nxb * 256;
  for (; i < n8; i += stride) {
    float4 v0 = ((const float4*)x)[2 * i];
    float4 v1 = ((const float4*)x)[2 * i + 1];
    union { unsigned short u[8]; uint4 v; } tv;
    tv.u[0] = f2bf(v0.x); tv.u[1] = f2bf(v0.y);
    tv.u[2] = f2bf(v0.z); tv.u[3] = f2bf(v0.w);
    tv.u[4] = f2bf(v1.x); tv.u[5] = f2bf(v1.y);
    tv.u[6] = f2bf(v1.z); tv.u[7] = f2bf(v1.w);
    ((uint4*)xb)[i] = tv.v;
  }
}

// ---------------- CSR build, phase B ----------------
// one WG per bucket: cross-bucket prefix from btot, LDS 256-node histogram +
// scan -> offs/cnt/inv, then csr fill with LDS cursors. Stage entries packed.
__global__ __launch_bounds__(256) void bucket_fill2(
    const unsigned* __restrict__ stage, const int* __restrict__ btot,
    int* __restrict__ offs, int* __restrict__ cnt, float* __restrict__ inv,
    int* __restrict__ csr, int N) {
  __shared__ int lhist[256];
  __shared__ int lscan[256];
  __shared__ int lcur[256];
  __shared__ int red[256];
  const int b = blockIdx.x;
  const int t = threadIdx.x;
  int sum = 0;
  for (int j = t; j < b; j += 256) sum += btot[j];
  red[t] = sum;
  lhist[t] = 0;
  __syncthreads();
  for (int d = 128; d; d >>= 1) {
    if (t < d) red[t] += red[t + d];
    __syncthreads();
  }
  const int base = red[0];
  const int count = btot[b];
  const unsigned* sp = stage + (size_t)b * CAP;
  for (int i = t; i < count; i += 256)
    atomicAdd(&lhist[sp[i] & 255u], 1);
  __syncthreads();
  int v = lhist[t];
  lscan[t] = v;
  __syncthreads();
  for (int d = 1; d < 256; d <<= 1) {
    int tv = (t >= d) ? lscan[t - d] : 0;
    __syncthreads();
    lscan[t] += tv;
    __syncthreads();
  }
  const int excl = lscan[t] - v;
  const int node = b * 256 + t;
  if (node < N) {
    offs[node] = base + excl;
    cnt[node] = v;
    inv[node] = 1.0f / (float)((v > 1) ? v : 1);
  }
  lcur[t] = base + excl;
  __syncthreads();
  for (int i = t; i < count; i += 256) {
    unsigned sd = sp[i];
    int p = atomicAdd(&lcur[sd & 255u], 1);
    csr[p] = (int)(sd >> 8);
  }
}

// ---------------- mean-aggregate: M[n] = inv[n] * sum_{j in N(n)} A[j] ----------------
// one wave per 2 consecutive nodes; 4 edge-slots x 16 column-lanes.
// Deep prefetch: when T>32, ALL 16 addresses are shfl'd and ALL 16 loads
// issued before any accumulate (mean T = 32, so half the waves take this
// path — doubles bytes-in-flight exactly where the latency is).
__global__ __launch_bounds__(256, 4) void agg_mean(
    const unsigned short* __restrict__ A, const float* __restrict__ inv,
    const int* __restrict__ offs, const int* __restrict__ cnt,
    const int* __restrict__ csr, unsigned short* __restrict__ M, int n) {
  int pr = (int)((blockIdx.x * 256 + threadIdx.x) >> 6);
  int n0 = pr * 2;
  if (n0 >= n) return;
  const int n1 = n0 + 1;
  const bool has1 = (n1 < n);
  const int lane = threadIdx.x & 63;
  const int g = lane >> 4;      // edge slot 0..3
  const int l = lane & 15;      // column chunk: columns l*8 .. l*8+7
  const int deg0 = cnt[n0];
  const int deg1 = has1 ? cnt[n1] : 0;
  const int start = offs[n0];
  const int T = deg0 + deg1;    // CSR rows adjacent -> combined segment
  f32x2 acc0[4] = {{0.f, 0.f}, {0.f, 0.f}, {0.f, 0.f}, {0.f, 0.f}};
  f32x2 acc1[4] = {{0.f, 0.f}, {0.f, 0.f}, {0.f, 0.f}, {0.f, 0.f}};
  const char* Ab = (const char*)A + (size_t)l * 16;   // per-lane column base

  if (T <= 64) {
    // byte offset of each neighbor row (idx*256); shfl the offset directly
    int offb = ((lane < T) ? csr[start + lane] : 0) << 8;
    const bool twoB = (T > 32);   // wave-uniform
    int nbA[8], nbB[8];
    uint4 vA[8], vB[8];
#pragma unroll
    for (int j = 0; j < 8; ++j) nbA[j] = __shfl(offb, j * 4 + g);
    if (twoB) {
#pragma unroll
      for (int j = 0; j < 8; ++j) nbB[j] = __shfl(offb, 32 + j * 4 + g);
    }
#pragma unroll
    for (int j = 0; j < 8; ++j)
      vA[j] = *(const uint4*)(Ab + (size_t)(unsigned)nbA[j]);
    if (twoB) {
#pragma unroll
      for (int j = 0; j < 8; ++j)
        vB[j] = *(const uint4*)(Ab + (size_t)(unsigned)nbB[j]);
    }
#pragma unroll
    for (int j = 0; j < 8; ++j) {
      int e = j * 4 + g;
      if (e < deg0) addf2(acc0, vA[j]);
      else if (e < T) addf2(acc1, vA[j]);
    }
    if (twoB) {
#pragma unroll
      for (int j = 0; j < 8; ++j) {
        int e = 32 + j * 4 + g;
        if (e < deg0) addf2(acc0, vB[j]);
        else if (e < T) addf2(acc1, vB[j]);
      }
    }
  } else {
    // rare generic path (T > 64 essentially never at mean degree 16)
    for (int node = 0; node < 2; ++node) {
      int dg = node ? deg1 : deg0;
      int st = node ? (start + deg0) : start;
      for (int base = 0; base < dg; base += 64) {
        int m = dg - base;
        if (m > 64) m = 64;
        int offb = ((lane < m) ? csr[st + base + lane] : 0) << 8;
#pragma unroll 4
        for (int i = 0; i < m; i += 4) {
          int sl = i + g;
          int nbv = __shfl(offb, sl & 63);  // full-exec shfl
          if (sl < m) {
            uint4 v = *(const uint4*)(Ab + (size_t)(unsigned)nbv);
            if (node) addf2(acc1, v);
            else addf2(acc0, v);
          }
        }
      }
    }
  }

  // reduce the 4 edge-slots (lanes differing in bits 4..5)
#pragma unroll
  for (int k = 0; k < 4; ++k) {
    acc0[k].x += __shfl_xor(acc0[k].x, 16);
    acc0[k].x += __shfl_xor(acc0[k].x, 32);
    acc0[k].y += __shfl_xor(acc0[k].y, 16);
    acc0[k].y += __shfl_xor(acc0[k].y, 32);
    acc1[k].x += __shfl_xor(acc1[k].x, 16);
    acc1[k].x += __shfl_xor(acc1[k].x, 32);
    acc1[k].y += __shfl_xor(acc1[k].y, 16);
    acc1[k].y += __shfl_xor(acc1[k].y, 32);
  }

  const int c0 = l * 8 + g * 2;
  {
    float s = inv[n0];
    unsigned pkt = (unsigned)f2bf(acc0[g].x * s) |
                   ((unsigned)f2bf(acc0[g].y * s) << 16);
    *(unsigned*)(M + (size_t)n0 * 128 + c0) = pkt;
  }
  if (has1) {
    float s = inv[n1];
    unsigned pkt = (unsigned)f2bf(acc1[g].x * s) |
                   ((unsigned)f2bf(acc1[g].y * s) << 16);
    *(unsigned*)(M + (size_t)n1 * 128 + c0) = pkt;
  }
}

// ---------------- fused GEMM: out = Am@Wl^T + As@Wr^T + b (+relu) ----------------
// Both A-streams are bf16 [n,128]; W arrives pre-converted & pre-permuted in
// MFMA B-fragment order (Wp), so staging is a straight 64 KiB coalesced copy.
template <int RELU, int OUTBF>
__global__ __launch_bounds__(256) void gemm_fused(
    const unsigned short* __restrict__ Am,  // aggregated input -> Wl
    const unsigned short* __restrict__ As,  // self input -> Wr
    const unsigned short* __restrict__ Wp,  // [2*16384] bf16, fragment order
    const float* __restrict__ bias, void* __restrict__ outp, int n) {
  __shared__ unsigned short wsh[2 * 16384];  // 64 KiB
  const int tid = threadIdx.x;

  {
    const uint4* wsrc = (const uint4*)Wp;
    uint4* wdst = (uint4*)wsh;
#pragma unroll
    for (int it = 0; it < 16; ++it) {
      int id = it * 256 + tid;
      wdst[id] = wsrc[id];
    }
  }
  __syncthreads();

  const int lane = tid & 63;
  const int wave = tid >> 6;
  const int nn = lane & 15;
  const int quad = lane >> 4;
  const int rowbase = blockIdx.x * 64 + wave * 16;

  int nodeA = rowbase + nn;
  if (nodeA > n - 1) nodeA = n - 1;

  short8 am[4], asf[4];
#pragma unroll
  for (int s = 0; s < 4; ++s) {
    am[s] = *(const short8*)(Am + (size_t)nodeA * 128 + s * 32 + quad * 8);
    asf[s] = *(const short8*)(As + (size_t)nodeA * 128 + s * 32 + quad * 8);
  }

  f32x4 acc[8];
#pragma unroll
  for (int jt = 0; jt < 8; ++jt) acc[jt] = (f32x4){0.f, 0.f, 0.f, 0.f};

#pragma unroll
  for (int jt = 0; jt < 8; ++jt) {
#pragma unroll
    for (int s = 0; s < 4; ++s) {
      int c = (s * 8 + jt) * 4 + quad;
      short8 bl = *(const short8*)(wsh + (c * 16 + nn) * 8);
      short8 br = *(const short8*)(wsh + 16384 + (c * 16 + nn) * 8);
      acc[jt] = __builtin_amdgcn_mfma_f32_16x16x32_bf16(am[s], bl, acc[jt], 0, 0, 0);
      acc[jt] = __builtin_amdgcn_mfma_f32_16x16x32_bf16(asf[s], br, acc[jt], 0, 0, 0);
    }
  }

#pragma unroll
  for (int jt = 0; jt < 8; ++jt) {
    int col = jt * 16 + nn;
    float bv = bias[col];
#pragma unroll
    for (int r = 0; r < 4; ++r) {
      int ro = rowbase + quad * 4 + r;
      if (ro < n) {
        float o = acc[jt][r] + bv;
        if (RELU) o = fmaxf(o, 0.f);
        if (OUTBF) {
          ((unsigned short*)outp)[(size_t)ro * 128 + col] = f2bf(o);
        } else {
          ((float*)outp)[(size_t)ro * 128 + col] = o;
        }
      }
    }
  }
}

// ---------------- launch ----------------
// Round-3 split structure (verified best; coop mega-fusion and in-kernel
// agg+gemm fusion both empirically refuted — see session notes).
//   M = mean_agg(A); out = M@Wl^T + A@Wr^T + b
// Buffers: xb (bf16 x) lives in d_out (dead before final gemm writes it);
//          stage (packed 4B) / hb share a ws region.

extern "C" void kernel_launch(void* const* d_in, const int* in_sizes, int n_in,
                              void* d_out, int out_size, void* d_ws, size_t ws_size,
                              hipStream_t stream) {
  const float* x = (const float*)d_in[0];
  const int* ei = (const int*)d_in[1];
  const float* W1l = (const float*)d_in[2];
  const float* b1 = (const float*)d_in[3];
  const float* W1r = (const float*)d_in[4];
  const float* W2l = (const float*)d_in[5];
  const float* b2 = (const float*)d_in[6];
  const float* W2r = (const float*)d_in[7];
  float* out = (float*)d_out;

  const int N = in_sizes[0] / 128;
  const int E = in_sizes[1] / 2;
  const int nb = (N + 255) / 256;   // buckets of 256 nodes; must be <= NBMAX

  char* p = (char*)d_ws;
  auto alloc = [&](size_t bytes) {
    char* r = p;
    p += (bytes + 255) & ~(size_t)255;
    return r;
  };
  int* btot = (int*)alloc((size_t)NBMAX * 4);
  int* cnt = (int*)alloc((size_t)N * 4);
  int* offs = (int*)alloc((size_t)N * 4);
  float* inv = (float*)alloc((size_t)N * 4);
  int* csr = (int*)alloc((size_t)E * 4);
  unsigned short* Mb = (unsigned short*)alloc((size_t)N * 128 * 2);   // 25.6 MB
  unsigned short* Wpb = (unsigned short*)alloc((size_t)4 * 16384 * 2); // 128 KB
  size_t stage_bytes = (size_t)nb * CAP * 4;   // packed 4B entries
  size_t hb_bytes = (size_t)N * 128 * 2;
  char* shared_region = alloc(stage_bytes > hb_bytes ? stage_bytes : hb_bytes);
  unsigned short* hb = (unsigned short*)shared_region;  // h (bf16) after CSR done
  unsigned* stage = (unsigned*)shared_region;           // staging during CSR build

  // xb: bf16 cast of x, parked in d_out (only the last gemm writes d_out)
  unsigned short* xb = (unsigned short*)d_out;

  hipMemsetAsync(btot, 0, (size_t)nb * 4, stream);

  const int SB = (E + 2047) / 2048;
  prep<<<SB + 4 + 2048, 256, 0, stream>>>(ei, E, btot, stage, SB,
                                          x, xb, N * 128 / 8,
                                          W1l, W1r, W2l, W2r, Wpb);
  bucket_fill2<<<nb, 256, 0, stream>>>(stage, btot, offs, cnt, inv, csr, N);

  const int gb = (N + 63) / 64;
  const int pairs = (N + 1) / 2;
  const int ab2 = (pairs + 3) / 4;   // 4 waves (=4 pairs) per 256-thread block

  // layer 1: M1 = mean_agg(xb); h = relu(M1@W1l^T + xb@W1r^T + b1) -> hb (bf16)
  agg_mean<<<ab2, 256, 0, stream>>>(xb, inv, offs, cnt, csr, Mb, N);
  gemm_fused<1, 1><<<gb, 256, 0, stream>>>(Mb, xb, Wpb, b1, (void*)hb, N);
  // layer 2: M2 = mean_agg(hb); out = M2@W2l^T + hb@W2r^T + b2 -> d_out (f32)
  agg_mean<<<ab2, 256, 0, stream>>>(hb, inv, offs, cnt, csr, Mb, N);
  gemm_fused<0, 0><<<gb, 256, 0, stream>>>(Mb, hb, Wpb + 32768, b2, (void*)out, N);
}

// Round 9
// 310.788 us; speedup vs baseline: 3.3692x; 1.1041x over previous
//
#include <hip/hip_runtime.h>

typedef __attribute__((ext_vector_type(8))) short short8;
typedef __attribute__((ext_vector_type(4))) float f32x4;
typedef __attribute__((ext_vector_type(2))) float f32x2;

#define NBMAX 512
#define CAP 8192   // per-bucket stage capacity; mean load 4096, sigma ~64

__device__ inline unsigned short f2bf(float f) {
  union { float f; unsigned u; } v; v.f = f;
  unsigned r = v.u + 0x7fffu + ((v.u >> 16) & 1u);
  return (unsigned short)(r >> 16);
}

// packed accumulate: uint4 of 8 bf16 -> 4x f32x2 (v_pk_add_f32)
__device__ inline void addf2(f32x2 (&a)[4], uint4 v) {
  union { uint2 u; f32x2 f; } t;
  t.u.x = v.x << 16; t.u.y = v.x & 0xffff0000u; a[0] += t.f;
  t.u.x = v.y << 16; t.u.y = v.y & 0xffff0000u; a[1] += t.f;
  t.u.x = v.z << 16; t.u.y = v.z & 0xffff0000u; a[2] += t.f;
  t.u.x = v.w << 16; t.u.y = v.w & 0xffff0000u; a[3] += t.f;
}

__device__ inline int load_src(const int* ei, int E, int e, int f64) {
  return f64 ? ei[2 * e] : ei[e];
}
__device__ inline int load_dst(const int* ei, int E, int e, int f64) {
  return f64 ? ei[2 * (E + e)] : ei[E + e];
}

// ---------------- prep: scatter (CSR phase A) + x->bf16 cast + W permute ----------------
// One launch, three block ranges:
//   [0, SB)        : edge scatter into bucket stage (dst>>8 buckets), 4096/block
//   [SB, SB+4)     : one-time W cast+permute into MFMA B-fragment order
//   [SB+4, ...)    : x (f32) -> xb (bf16) streaming cast
// Staged edge PACKED to 4B: (src << 8) | (dst & 255)  [src < 2^24].
__global__ __launch_bounds__(256) void prep(
    const int* __restrict__ ei, int E,
    int* __restrict__ btot, unsigned* __restrict__ stage, int SB,
    const float* __restrict__ x, unsigned short* __restrict__ xb, int n8,
    const float* __restrict__ W1l, const float* __restrict__ W1r,
    const float* __restrict__ W2l, const float* __restrict__ W2r,
    unsigned short* __restrict__ Wp) {
  __shared__ int lcnt[NBMAX];
  __shared__ int lbase[NBMAX];
  __shared__ int sflag;
  const int b = blockIdx.x;
  const int t = threadIdx.x;

  if (b < SB) {
    // ---- scatter (4096 edges per block) ----
    if (t == 0) sflag = 0;
    for (int i = t; i < NBMAX; i += 256) lcnt[i] = 0;
    __syncthreads();
    const int e0 = b * 4096;
    {
      int e = e0 + t;
      int v = (e < E) ? ei[2 * e + 1] : 0;   // in-bounds under both layouts
      if (v) atomicOr(&sflag, 1);
    }
    __syncthreads();
    const int f64 = (sflag == 0) ? 1 : 0;

    unsigned pk[16];
    int bks[16];
#pragma unroll
    for (int i = 0; i < 16; ++i) {
      int e = e0 + i * 256 + t;
      if (e < E) {
        int s = load_src(ei, E, e, f64);
        int d = load_dst(ei, E, e, f64);
        pk[i] = ((unsigned)s << 8) | ((unsigned)d & 255u);
        bks[i] = d >> 8;
        atomicAdd(&lcnt[d >> 8], 1);
      } else {
        bks[i] = -1;
      }
    }
    __syncthreads();
    for (int i = t; i < NBMAX; i += 256) {
      int c = lcnt[i];
      lbase[i] = c ? atomicAdd(&btot[i], c) : 0;
    }
    __syncthreads();
    for (int i = t; i < NBMAX; i += 256) lcnt[i] = 0;
    __syncthreads();
#pragma unroll
    for (int i = 0; i < 16; ++i) {
      int bk = bks[i];
      if (bk >= 0) {
        int r = atomicAdd(&lcnt[bk], 1);
        stage[(size_t)bk * CAP + lbase[bk] + r] = pk[i];
      }
    }
    return;
  }

  if (b < SB + 4) {
    // ---- W cast + permute (grid-invariant, done once) ----
    const int m = b - SB;
    const float* W = (m == 0) ? W1l : (m == 1) ? W1r : (m == 2) ? W2l : W2r;
    unsigned short* dst = Wp + (size_t)m * 16384;
#pragma unroll
    for (int it = 0; it < 8; ++it) {
      int id = it * 256 + t;
      int j = id >> 4;
      int kc = id & 15;
      int s = kc >> 2, q = kc & 3;
      int jt = j >> 4, nn2 = j & 15;
      int c = (s * 8 + jt) * 4 + q;
      const float* src = W + j * 128 + kc * 8;
      union { unsigned short u[8]; uint4 v; } tv;
#pragma unroll
      for (int k = 0; k < 8; ++k) tv.u[k] = f2bf(src[k]);
      *(uint4*)(dst + (c * 16 + nn2) * 8) = tv.v;
    }
    return;
  }

  // ---- x -> bf16 cast ----
  const int cb = b - SB - 4;
  const int nxb = gridDim.x - SB - 4;
  int i = cb * 256 + t;
  const int stride = nxb * 256;
  for (; i < n8; i += stride) {
    float4 v0 = ((const float4*)x)[2 * i];
    float4 v1 = ((const float4*)x)[2 * i + 1];
    union { unsigned short u[8]; uint4 v; } tv;
    tv.u[0] = f2bf(v0.x); tv.u[1] = f2bf(v0.y);
    tv.u[2] = f2bf(v0.z); tv.u[3] = f2bf(v0.w);
    tv.u[4] = f2bf(v1.x); tv.u[5] = f2bf(v1.y);
    tv.u[6] = f2bf(v1.z); tv.u[7] = f2bf(v1.w);
    ((uint4*)xb)[i] = tv.v;
  }
}

// ---------------- CSR build, phase B ----------------
// one WG per bucket: cross-bucket prefix from btot, LDS 256-node histogram +
// scan -> offs/cnt/inv, then csr fill with LDS cursors. Stage entries packed.
__global__ __launch_bounds__(256) void bucket_fill2(
    const unsigned* __restrict__ stage, const int* __restrict__ btot,
    int* __restrict__ offs, int* __restrict__ cnt, float* __restrict__ inv,
    int* __restrict__ csr, int N) {
  __shared__ int lhist[256];
  __shared__ int lscan[256];
  __shared__ int lcur[256];
  __shared__ int red[256];
  const int b = blockIdx.x;
  const int t = threadIdx.x;
  int sum = 0;
  for (int j = t; j < b; j += 256) sum += btot[j];
  red[t] = sum;
  lhist[t] = 0;
  __syncthreads();
  for (int d = 128; d; d >>= 1) {
    if (t < d) red[t] += red[t + d];
    __syncthreads();
  }
  const int base = red[0];
  const int count = btot[b];
  const unsigned* sp = stage + (size_t)b * CAP;
  for (int i = t; i < count; i += 256)
    atomicAdd(&lhist[sp[i] & 255u], 1);
  __syncthreads();
  int v = lhist[t];
  lscan[t] = v;
  __syncthreads();
  for (int d = 1; d < 256; d <<= 1) {
    int tv = (t >= d) ? lscan[t - d] : 0;
    __syncthreads();
    lscan[t] += tv;
    __syncthreads();
  }
  const int excl = lscan[t] - v;
  const int node = b * 256 + t;
  if (node < N) {
    offs[node] = base + excl;
    cnt[node] = v;
    inv[node] = 1.0f / (float)((v > 1) ? v : 1);
  }
  lcur[t] = base + excl;
  __syncthreads();
  for (int i = t; i < count; i += 256) {
    unsigned sd = sp[i];
    int p = atomicAdd(&lcur[sd & 255u], 1);
    csr[p] = (int)(sd >> 8);
  }
}

// ---------------- mean-aggregate: M[n] = inv[n] * sum_{j in N(n)} A[j] ----------------
// EXACT round-3 structure (proven 56.7 us): one wave per 2 consecutive nodes;
// 4 edge-slots x 16 column-lanes; per-chunk batch prefetch (8 shfls, 8 loads,
// accumulate) — deeper batching regresses via coarse vmcnt (round-8 lesson).
__global__ __launch_bounds__(256, 4) void agg_mean(
    const unsigned short* __restrict__ A, const float* __restrict__ inv,
    const int* __restrict__ offs, const int* __restrict__ cnt,
    const int* __restrict__ csr, unsigned short* __restrict__ M, int n) {
  int pr = (int)((blockIdx.x * 256 + threadIdx.x) >> 6);
  int n0 = pr * 2;
  if (n0 >= n) return;
  const int n1 = n0 + 1;
  const bool has1 = (n1 < n);
  const int lane = threadIdx.x & 63;
  const int g = lane >> 4;      // edge slot 0..3
  const int l = lane & 15;      // column chunk: columns l*8 .. l*8+7
  const int deg0 = cnt[n0];
  const int deg1 = has1 ? cnt[n1] : 0;
  const int start = offs[n0];
  const int T = deg0 + deg1;    // CSR rows adjacent -> combined segment
  f32x2 acc0[4] = {{0.f, 0.f}, {0.f, 0.f}, {0.f, 0.f}, {0.f, 0.f}};
  f32x2 acc1[4] = {{0.f, 0.f}, {0.f, 0.f}, {0.f, 0.f}, {0.f, 0.f}};
  const char* Ab = (const char*)A + (size_t)l * 16;   // per-lane column base

  if (T <= 64) {
    // byte offset of each neighbor row (idx*256); shfl the offset directly
    int offb = ((lane < T) ? csr[start + lane] : 0) << 8;
    {
      // chunk A: edges 0..31
      int nb2[8];
      uint4 vv[8];
#pragma unroll
      for (int j = 0; j < 8; ++j) nb2[j] = __shfl(offb, j * 4 + g);
#pragma unroll
      for (int j = 0; j < 8; ++j)
        vv[j] = *(const uint4*)(Ab + (size_t)(unsigned)nb2[j]);
#pragma unroll
      for (int j = 0; j < 8; ++j) {
        int e = j * 4 + g;
        if (e < deg0) addf2(acc0, vv[j]);
        else if (e < T) addf2(acc1, vv[j]);
      }
    }
    if (T > 32) {
      // chunk B: edges 32..63 (wave-uniform branch)
      int nb2[8];
      uint4 vv[8];
#pragma unroll
      for (int j = 0; j < 8; ++j) nb2[j] = __shfl(offb, 32 + j * 4 + g);
#pragma unroll
      for (int j = 0; j < 8; ++j)
        vv[j] = *(const uint4*)(Ab + (size_t)(unsigned)nb2[j]);
#pragma unroll
      for (int j = 0; j < 8; ++j) {
        int e = 32 + j * 4 + g;
        if (e < deg0) addf2(acc0, vv[j]);
        else if (e < T) addf2(acc1, vv[j]);
      }
    }
  } else {
    // rare generic path (T > 64 essentially never at mean degree 16)
    for (int node = 0; node < 2; ++node) {
      int dg = node ? deg1 : deg0;
      int st = node ? (start + deg0) : start;
      for (int base = 0; base < dg; base += 64) {
        int m = dg - base;
        if (m > 64) m = 64;
        int offb = ((lane < m) ? csr[st + base + lane] : 0) << 8;
#pragma unroll 4
        for (int i = 0; i < m; i += 4) {
          int sl = i + g;
          int nbv = __shfl(offb, sl & 63);  // full-exec shfl
          if (sl < m) {
            uint4 v = *(const uint4*)(Ab + (size_t)(unsigned)nbv);
            if (node) addf2(acc1, v);
            else addf2(acc0, v);
          }
        }
      }
    }
  }

  // reduce the 4 edge-slots (lanes differing in bits 4..5)
#pragma unroll
  for (int k = 0; k < 4; ++k) {
    acc0[k].x += __shfl_xor(acc0[k].x, 16);
    acc0[k].x += __shfl_xor(acc0[k].x, 32);
    acc0[k].y += __shfl_xor(acc0[k].y, 16);
    acc0[k].y += __shfl_xor(acc0[k].y, 32);
    acc1[k].x += __shfl_xor(acc1[k].x, 16);
    acc1[k].x += __shfl_xor(acc1[k].x, 32);
    acc1[k].y += __shfl_xor(acc1[k].y, 16);
    acc1[k].y += __shfl_xor(acc1[k].y, 32);
  }

  const int c0 = l * 8 + g * 2;
  {
    float s = inv[n0];
    unsigned pkt = (unsigned)f2bf(acc0[g].x * s) |
                   ((unsigned)f2bf(acc0[g].y * s) << 16);
    *(unsigned*)(M + (size_t)n0 * 128 + c0) = pkt;
  }
  if (has1) {
    float s = inv[n1];
    unsigned pkt = (unsigned)f2bf(acc1[g].x * s) |
                   ((unsigned)f2bf(acc1[g].y * s) << 16);
    *(unsigned*)(M + (size_t)n1 * 128 + c0) = pkt;
  }
}

// ---------------- fused GEMM: out = Am@Wl^T + As@Wr^T + b (+relu) ----------------
// PERSISTENT: 64 KiB LDS caps residency at 2 blocks/CU anyway, so use 512
// grid-striding blocks that stage W ONCE (single barrier; W read-only after),
// instead of 1563 one-shot blocks each re-staging 64 KiB.
template <int RELU, int OUTBF>
__global__ __launch_bounds__(256) void gemm_fused(
    const unsigned short* __restrict__ Am,  // aggregated input -> Wl
    const unsigned short* __restrict__ As,  // self input -> Wr
    const unsigned short* __restrict__ Wp,  // [2*16384] bf16, fragment order
    const float* __restrict__ bias, void* __restrict__ outp, int n,
    int nchunks) {
  __shared__ unsigned short wsh[2 * 16384];  // 64 KiB
  const int tid = threadIdx.x;

  {
    const uint4* wsrc = (const uint4*)Wp;
    uint4* wdst = (uint4*)wsh;
#pragma unroll
    for (int it = 0; it < 16; ++it) {
      int id = it * 256 + tid;
      wdst[id] = wsrc[id];
    }
  }
  __syncthreads();

  const int lane = tid & 63;
  const int wave = tid >> 6;
  const int nn = lane & 15;
  const int quad = lane >> 4;

  for (int ch = blockIdx.x; ch < nchunks; ch += gridDim.x) {
    const int rowbase = ch * 64 + wave * 16;
    int nodeA = rowbase + nn;
    if (nodeA > n - 1) nodeA = n - 1;

    short8 am[4], asf[4];
#pragma unroll
    for (int s = 0; s < 4; ++s) {
      am[s] = *(const short8*)(Am + (size_t)nodeA * 128 + s * 32 + quad * 8);
      asf[s] = *(const short8*)(As + (size_t)nodeA * 128 + s * 32 + quad * 8);
    }

    f32x4 acc[8];
#pragma unroll
    for (int jt = 0; jt < 8; ++jt) acc[jt] = (f32x4){0.f, 0.f, 0.f, 0.f};

#pragma unroll
    for (int jt = 0; jt < 8; ++jt) {
#pragma unroll
      for (int s = 0; s < 4; ++s) {
        int c = (s * 8 + jt) * 4 + quad;
        short8 bl = *(const short8*)(wsh + (c * 16 + nn) * 8);
        short8 br = *(const short8*)(wsh + 16384 + (c * 16 + nn) * 8);
        acc[jt] = __builtin_amdgcn_mfma_f32_16x16x32_bf16(am[s], bl, acc[jt], 0, 0, 0);
        acc[jt] = __builtin_amdgcn_mfma_f32_16x16x32_bf16(asf[s], br, acc[jt], 0, 0, 0);
      }
    }

#pragma unroll
    for (int jt = 0; jt < 8; ++jt) {
      int col = jt * 16 + nn;
      float bv = bias[col];
#pragma unroll
      for (int r = 0; r < 4; ++r) {
        int ro = rowbase + quad * 4 + r;
        if (ro < n) {
          float o = acc[jt][r] + bv;
          if (RELU) o = fmaxf(o, 0.f);
          if (OUTBF) {
            ((unsigned short*)outp)[(size_t)ro * 128 + col] = f2bf(o);
          } else {
            ((float*)outp)[(size_t)ro * 128 + col] = o;
          }
        }
      }
    }
  }
}

// ---------------- launch ----------------
// Round-3 split structure (verified best; coop mega-fusion, in-kernel
// agg+gemm fusion, and deep gather prefetch all empirically refuted).
//   M = mean_agg(A); out = M@Wl^T + A@Wr^T + b
// Buffers: xb (bf16 x) lives in d_out (dead before final gemm writes it);
//          stage (packed 4B) / hb share a ws region.

extern "C" void kernel_launch(void* const* d_in, const int* in_sizes, int n_in,
                              void* d_out, int out_size, void* d_ws, size_t ws_size,
                              hipStream_t stream) {
  const float* x = (const float*)d_in[0];
  const int* ei = (const int*)d_in[1];
  const float* W1l = (const float*)d_in[2];
  const float* b1 = (const float*)d_in[3];
  const float* W1r = (const float*)d_in[4];
  const float* W2l = (const float*)d_in[5];
  const float* b2 = (const float*)d_in[6];
  const float* W2r = (const float*)d_in[7];
  float* out = (float*)d_out;

  const int N = in_sizes[0] / 128;
  const int E = in_sizes[1] / 2;
  const int nb = (N + 255) / 256;   // buckets of 256 nodes; must be <= NBMAX

  char* p = (char*)d_ws;
  auto alloc = [&](size_t bytes) {
    char* r = p;
    p += (bytes + 255) & ~(size_t)255;
    return r;
  };
  int* btot = (int*)alloc((size_t)NBMAX * 4);
  int* cnt = (int*)alloc((size_t)N * 4);
  int* offs = (int*)alloc((size_t)N * 4);
  float* inv = (float*)alloc((size_t)N * 4);
  int* csr = (int*)alloc((size_t)E * 4);
  unsigned short* Mb = (unsigned short*)alloc((size_t)N * 128 * 2);   // 25.6 MB
  unsigned short* Wpb = (unsigned short*)alloc((size_t)4 * 16384 * 2); // 128 KB
  size_t stage_bytes = (size_t)nb * CAP * 4;   // packed 4B entries
  size_t hb_bytes = (size_t)N * 128 * 2;
  char* shared_region = alloc(stage_bytes > hb_bytes ? stage_bytes : hb_bytes);
  unsigned short* hb = (unsigned short*)shared_region;  // h (bf16) after CSR done
  unsigned* stage = (unsigned*)shared_region;           // staging during CSR build

  // xb: bf16 cast of x, parked in d_out (only the last gemm writes d_out)
  unsigned short* xb = (unsigned short*)d_out;

  hipMemsetAsync(btot, 0, (size_t)nb * 4, stream);

  const int SB = (E + 4095) / 4096;
  prep<<<SB + 4 + 2048, 256, 0, stream>>>(ei, E, btot, stage, SB,
                                          x, xb, N * 128 / 8,
                                          W1l, W1r, W2l, W2r, Wpb);
  bucket_fill2<<<nb, 256, 0, stream>>>(stage, btot, offs, cnt, inv, csr, N);

  const int gb = (N + 63) / 64;
  const int PB = gb < 512 ? gb : 512;   // persistent gemm grid (2 blocks/CU)
  const int pairs = (N + 1) / 2;
  const int ab2 = (pairs + 3) / 4;   // 4 waves (=4 pairs) per 256-thread block

  // layer 1: M1 = mean_agg(xb); h = relu(M1@W1l^T + xb@W1r^T + b1) -> hb (bf16)
  agg_mean<<<ab2, 256, 0, stream>>>(xb, inv, offs, cnt, csr, Mb, N);
  gemm_fused<1, 1><<<PB, 256, 0, stream>>>(Mb, xb, Wpb, b1, (void*)hb, N, gb);
  // layer 2: M2 = mean_agg(hb); out = M2@W2l^T + hb@W2r^T + b2 -> d_out (f32)
  agg_mean<<<ab2, 256, 0, stream>>>(hb, inv, offs, cnt, csr, Mb, N);
  gemm_fused<0, 0><<<PB, 256, 0, stream>>>(Mb, hb, Wpb + 32768, b2, (void*)out, N, gb);
}